// Round 8
// baseline (447.814 us; speedup 1.0000x reference)
//
#include <hip/hip_runtime.h>
#include <stdint.h>
#include <stddef.h>

typedef unsigned short u16;
typedef __attribute__((ext_vector_type(8))) short short8;
typedef __attribute__((ext_vector_type(4))) float f32x4;
typedef __attribute__((ext_vector_type(4))) unsigned short ushort4v;
typedef __attribute__((ext_vector_type(4))) unsigned char uchar4v;
typedef __attribute__((ext_vector_type(2))) unsigned int uint2v;

constexpr int B_ = 8, S_ = 1024, HID_ = 1024, NH_ = 16, HD_ = 64;
// log2(e) folded into Q-scale / rel-fold / shift so softmax is a bare v_exp_f32.
#define LOG2E_F 1.4426950408889634f
#define QSCALE_F 0.18033688011112043f   /* 0.125 * log2(e) */
#define SHIFT2_F 11.541560327111707f    /* 8 * log2(e) */

__device__ __forceinline__ u16 f2b(float f) {
  unsigned int u = __builtin_bit_cast(unsigned int, f);
  u += 0x7fff + ((u >> 16) & 1);   // RNE
  return (u16)(u >> 16);
}
__device__ __forceinline__ float b2f(u16 s) {
  unsigned int u = ((unsigned int)s) << 16;
  return __builtin_bit_cast(float, u);
}
// 2^x. MUST be compiler-emitted (trans-op read hazard: inline-asm v_exp_f32 is
// invisible to the hazard recognizer -> stale-register reads; caused r2/r3 fails).
__device__ __forceinline__ float fexp2(float x) {
#if __has_builtin(__builtin_amdgcn_exp2f)
  return __builtin_amdgcn_exp2f(x);
#else
  return exp2f(x);
#endif
}
__device__ __forceinline__ void llds16(const void* g, void* l) {
  __builtin_amdgcn_global_load_lds((__attribute__((address_space(1))) void*)g,
                                   (__attribute__((address_space(3))) void*)l, 16, 0, 0);
}

// ---------------- fp32 -> bf16 conversions (8 floats/thread, 16B stores) -------
__global__ __launch_bounds__(256) void prep_cvt(
    const float* __restrict__ x, const float* __restrict__ wqkv,
    const float* __restrict__ wout, u16* __restrict__ xb,
    u16* __restrict__ wqkvb, u16* __restrict__ woutb) {
  const int NX8 = B_ * S_ * HID_ / 8, NW18 = 3 * HID_ * HID_ / 8, NW28 = HID_ * HID_ / 8;
  const int tot = NX8 + NW18 + NW28;
  for (int i = blockIdx.x * blockDim.x + threadIdx.x; i < tot; i += gridDim.x * blockDim.x) {
    const float4* s; u16* d; int j;
    if (i < NX8)              { s = (const float4*)x;    d = xb;    j = i; }
    else if (i < NX8 + NW18)  { s = (const float4*)wqkv; d = wqkvb; j = i - NX8; }
    else                      { s = (const float4*)wout; d = woutb; j = i - NX8 - NW18; }
    float4 v0 = s[2 * (size_t)j], v1 = s[2 * (size_t)j + 1];
    short8 o;
    o[0] = (short)f2b(v0.x); o[1] = (short)f2b(v0.y);
    o[2] = (short)f2b(v0.z); o[3] = (short)f2b(v0.w);
    o[4] = (short)f2b(v1.x); o[5] = (short)f2b(v1.y);
    o[6] = (short)f2b(v1.z); o[7] = (short)f2b(v1.w);
    *(short8*)(d + 8 * (size_t)j) = o;
  }
}

// ---------------- QKV projection GEMM, D[o][s], BK=64 ----------------
// XCD-chunked 1D grid (1536 = 8*192, o-fastest in chunk).
// Q/K: LDS-transposed coalesced epilogue to [B,NH,S,HD].
// V: transposed epilogue -> Vt[B,NH,HD,S] directly.
__global__ __launch_bounds__(256) void gemm_qkv(
    const u16* __restrict__ W, const u16* __restrict__ X,
    const float* __restrict__ qbias, const float* __restrict__ vbias,
    u16* __restrict__ Qb, u16* __restrict__ Kb, u16* __restrict__ Vtb) {
  constexpr int K = HID_;
  __shared__ u16 smem[128 * 136];           // 4x4096 staging overlaid with epilogue buf
  u16* Ws0 = smem;
  u16* Ws1 = smem + 4096;
  u16* Xs0 = smem + 8192;
  u16* Xs1 = smem + 12288;
  const int lin = blockIdx.x;
  const int virt = (lin & 7) * 192 + (lin >> 3);
  const int o0 = (virt % 24) * 128, s0 = (virt / 24) * 128;
  const int t = threadIdx.x, lane = t & 63, wv = t >> 6;
  const int wr = wv >> 1, wc = wv & 1, ln = lane & 15, q8 = lane >> 4;
  f32x4 acc[4][4] = {};

  for (int kt = 0; kt < K / 64; ++kt) {
    const int k0 = kt * 64;
#pragma unroll
    for (int c = 0; c < 2; ++c) {
      int idx = c * 256 + t, row = idx >> 2, cc = (idx & 3) * 8;
      const int db = (c * 256 + wv * 64) * 8;
      llds16(W + (size_t)(o0 + row) * K + k0 + cc,      Ws0 + db);
      llds16(W + (size_t)(o0 + row) * K + k0 + 32 + cc, Ws1 + db);
      llds16(X + (size_t)(s0 + row) * K + k0 + cc,      Xs0 + db);
      llds16(X + (size_t)(s0 + row) * K + k0 + 32 + cc, Xs1 + db);
    }
    __syncthreads();
#pragma unroll
    for (int hh = 0; hh < 2; ++hh) {
      const u16* Wh = hh ? Ws1 : Ws0;
      const u16* Xh = hh ? Xs1 : Xs0;
      short8 of[4], sf[4];
#pragma unroll
      for (int mi = 0; mi < 4; ++mi)
        of[mi] = *(const short8*)(Wh + (wr * 64 + mi * 16 + ln) * 32 + q8 * 8);
#pragma unroll
      for (int ni = 0; ni < 4; ++ni)
        sf[ni] = *(const short8*)(Xh + (wc * 64 + ni * 16 + ln) * 32 + q8 * 8);
#pragma unroll
      for (int mi = 0; mi < 4; ++mi)
#pragma unroll
        for (int ni = 0; ni < 4; ++ni)
          acc[mi][ni] = __builtin_amdgcn_mfma_f32_16x16x32_bf16(of[mi], sf[ni], acc[mi][ni], 0, 0, 0);
    }
    __syncthreads();
  }

  const int sec = o0 >> 10;   // 0=Q 1=K 2=V (block-uniform)

  if (sec == 2) {
    // ----- V: transposed epilogue, write Vt[b,h,d,s] directly -----
#pragma unroll
    for (int mi = 0; mi < 4; ++mi) {
      const int ocol = wr * 64 + mi * 16 + q8 * 4;
      const int oo = (o0 + ocol) & 1023;
      float4 b4 = *(const float4*)(vbias + oo);
#pragma unroll
      for (int ni = 0; ni < 4; ++ni) {
        const int srow = wc * 64 + ni * 16 + ln;
#pragma unroll
        for (int r = 0; r < 4; ++r)
          smem[(ocol + r) * 136 + srow] = f2b(acc[mi][ni][r] + ((const float*)&b4)[r]);
      }
    }
    __syncthreads();
#pragma unroll
    for (int i = 0; i < 8; ++i) {
      int flat = i * 256 + t;
      int dl = flat >> 4, s8 = (flat & 15) * 8;
      short8 v = *(const short8*)(smem + dl * 136 + s8);
      int oo = (o0 + dl) & 1023, hh = oo >> 6, dd = oo & 63;
      int bb = s0 >> 10, ss = (s0 + s8) & 1023;
      *(short8*)(Vtb + ((size_t)(bb * NH_ + hh) * HD_ + dd) * S_ + ss) = v;
    }
    return;
  }

  // ----- Q/K: phase 1: bias/scale applied, bf16 into buf[s 128][o 128, pitch 136]
#pragma unroll
  for (int mi = 0; mi < 4; ++mi) {
    const int ocol = wr * 64 + mi * 16 + q8 * 4;
    const int oo = (o0 + ocol) & 1023;
    float4 b4;
    if (sec == 0) b4 = *(const float4*)(qbias + oo);
    else          b4 = float4{0.f, 0.f, 0.f, 0.f};
#pragma unroll
    for (int ni = 0; ni < 4; ++ni) {
      const int srow = wc * 64 + ni * 16 + ln;
      u16 e[4];
#pragma unroll
      for (int r = 0; r < 4; ++r) {
        float v = acc[mi][ni][r] + ((const float*)&b4)[r];
        if (sec == 0) v *= QSCALE_F;   // 1/sqrt(64) * log2(e)
        e[r] = f2b(v);
      }
      uint2v pw;
      pw[0] = (unsigned)e[0] | ((unsigned)e[1] << 16);
      pw[1] = (unsigned)e[2] | ((unsigned)e[3] << 16);
      *(uint2v*)(smem + srow * 136 + ocol) = pw;
    }
  }
  __syncthreads();
  u16* dst = (sec == 0) ? Qb : Kb;
#pragma unroll
  for (int i = 0; i < 8; ++i) {
    int flat = i * 256 + t;
    int srow = flat >> 4, c8 = (flat & 15) * 8;
    short8 v = *(const short8*)(smem + srow * 136 + c8);
    int oo = (o0 + c8) & 1023, hh = oo >> 6, dd = oo & 63;
    int s = s0 + srow, bb = s >> 10, ss = s & 1023;
    *(short8*)(dst + ((size_t)(bb * NH_ + hh) * S_ + ss) * HD_ + dd) = v;
  }
}

// ---------------- flash attention: S^T = K·Q^T, fixed-shift softmax, O^T = V^T·P^T ----
// 512 threads (8 waves), 256 q-rows per block, grid 512, XCD-chunked decode.
// rel_pos/rel_2d are read DIRECTLY as fp32 (float4 per fragment row) and folded
// (a+b)*log2e + mbase in-loop: kills the rel_perm kernel. The 8 b-sharers of a
// rel slice are consecutive blocks on one XCD -> one L2 fill serves all 8.
__global__ __launch_bounds__(512, 2) void flash_attn(
    const u16* __restrict__ Qb, const u16* __restrict__ Kb,
    const u16* __restrict__ Vtb, const float* __restrict__ relp,
    const float* __restrict__ rel2,
    const unsigned char* __restrict__ mask, u16* __restrict__ ctxb) {
  const int lin = blockIdx.x;
  const int virt = (lin & 7) * 64 + (lin >> 3);
  const int h = virt >> 5, qt_blk = (virt >> 3) & 3, b = virt & 7;
  const int bh = b * NH_ + h, q0 = qt_blk * 256;
  const int t = threadIdx.x, lane = t & 63, wv = t >> 6;
  const int ln = lane & 15, q8 = lane >> 4;

  __shared__ u16 smem[28160];          // Ks 128*72 | Vts 64*136 | Pbuf 8*32*40 = 55 KB
  u16* Ks  = smem;                     // [k 128][64+8]
  u16* Vts = smem + 9216;              // [d 64][128+8]
  u16* Pw  = smem + 17920 + wv * 1280; // per-wave [q 32][32+8]

  const int krow = t >> 3, kcol = (t & 7) * 8;   // 64 k-rows per pass
  const int vrow = t >> 4, vcol = (t & 15) * 8;  // 32 d-rows per pass

  // per-lane fp32 rel bases (row q0+wv*32+ln; +qt*16*S_ selects the qt row)
  const float* relA = relp + ((size_t)h * S_ + q0 + wv * 32 + ln) * S_;
  const float* relB = rel2 + ((size_t)h * S_ + q0 + wv * 32 + ln) * S_;

  short8 kreg[2], vreg[2];
#pragma unroll
  for (int i = 0; i < 2; ++i)
    kreg[i] = *(const short8*)(Kb + ((size_t)bh * S_ + i * 64 + krow) * HD_ + kcol);
#pragma unroll
  for (int i = 0; i < 2; ++i)
    vreg[i] = *(const short8*)(Vtb + ((size_t)bh * HD_ + i * 32 + vrow) * S_ + vcol);

  short8 qf[2][2];
#pragma unroll
  for (int qt = 0; qt < 2; ++qt)
#pragma unroll
    for (int kc = 0; kc < 2; ++kc)
      qf[qt][kc] = *(const short8*)(Qb + ((size_t)bh * S_ + q0 + wv * 32 + qt * 16 + ln) * HD_ + kc * 32 + q8 * 8);

  f32x4 Oa[4][2] = {};   // [mt(d)][qt]
  float rs2[2] = {0.f, 0.f};

  for (int kt128 = 0; kt128 < 8; ++kt128) {
    const int k0 = kt128 * 128;

    // mask burst for this iteration (8 VGPRs)
    uchar4v mg[4][2];
#pragma unroll
    for (int kvc = 0; kvc < 4; ++kvc)
#pragma unroll
      for (int sub = 0; sub < 2; ++sub)
        mg[kvc][sub] = *(const uchar4v*)(mask + b * S_ + k0 + (kvc * 2 + sub) * 16 + q8 * 4);

    __syncthreads();
#pragma unroll
    for (int i = 0; i < 2; ++i)
      *(short8*)(Ks + (i * 64 + krow) * 72 + kcol) = kreg[i];
#pragma unroll
    for (int i = 0; i < 2; ++i)
      *(short8*)(Vts + (i * 32 + vrow) * 136 + vcol) = vreg[i];
    if (kt128 < 7) {
      const int k0n = k0 + 128;
#pragma unroll
      for (int i = 0; i < 2; ++i)
        kreg[i] = *(const short8*)(Kb + ((size_t)bh * S_ + k0n + i * 64 + krow) * HD_ + kcol);
#pragma unroll
      for (int i = 0; i < 2; ++i)
        vreg[i] = *(const short8*)(Vtb + ((size_t)bh * HD_ + i * 32 + vrow) * S_ + k0n + vcol);
    }
    __syncthreads();

#pragma unroll
    for (int kvc = 0; kvc < 4; ++kvc) {
#pragma unroll
      for (int sub = 0; sub < 2; ++sub) {
        const int kt = kvc * 2 + sub;
        const int kg = k0 + kt * 16 + q8 * 4;
        short8 kf0 = *(const short8*)(Ks + (kt * 16 + ln) * 72 + q8 * 8);
        short8 kf1 = *(const short8*)(Ks + (kt * 16 + ln) * 72 + 32 + q8 * 8);
        uchar4v m4 = mg[kvc][sub];
        f32x4 mbase;
#pragma unroll
        for (int r = 0; r < 4; ++r) mbase[r] = (m4[r] ? -1e30f : 0.f) - SHIFT2_F;
#pragma unroll
        for (int qt = 0; qt < 2; ++qt) {
          float4 ra = *(const float4*)(relA + (size_t)(qt * 16) * S_ + kg);
          float4 rb = *(const float4*)(relB + (size_t)(qt * 16) * S_ + kg);
          f32x4 sc;
          sc[0] = (ra.x + rb.x) * LOG2E_F + mbase[0];
          sc[1] = (ra.y + rb.y) * LOG2E_F + mbase[1];
          sc[2] = (ra.z + rb.z) * LOG2E_F + mbase[2];
          sc[3] = (ra.w + rb.w) * LOG2E_F + mbase[3];
          sc = __builtin_amdgcn_mfma_f32_16x16x32_bf16(kf0, qf[qt][0], sc, 0, 0, 0);
          sc = __builtin_amdgcn_mfma_f32_16x16x32_bf16(kf1, qf[qt][1], sc, 0, 0, 0);
          // scores pre-scaled by log2(e): single hardware v_exp_f32 each
          float p0 = fexp2(sc[0]), p1 = fexp2(sc[1]);
          float p2 = fexp2(sc[2]), p3 = fexp2(sc[3]);
          rs2[qt] += (p0 + p1) + (p2 + p3);
          uint2v pw;
          pw[0] = (unsigned)f2b(p0) | ((unsigned)f2b(p1) << 16);
          pw[1] = (unsigned)f2b(p2) | ((unsigned)f2b(p3) << 16);
          *(uint2v*)(Pw + (qt * 16 + ln) * 40 + sub * 16 + q8 * 4) = pw;
        }
      }
      short8 pf0 = *(const short8*)(Pw + ln * 40 + q8 * 8);
      short8 pf1 = *(const short8*)(Pw + (16 + ln) * 40 + q8 * 8);
#pragma unroll
      for (int mt = 0; mt < 4; ++mt) {
        short8 vf = *(const short8*)(Vts + (mt * 16 + ln) * 136 + kvc * 32 + q8 * 8);
        Oa[mt][0] = __builtin_amdgcn_mfma_f32_16x16x32_bf16(vf, pf0, Oa[mt][0], 0, 0, 0);
        Oa[mt][1] = __builtin_amdgcn_mfma_f32_16x16x32_bf16(vf, pf1, Oa[mt][1], 0, 0, 0);
      }
    }
  }

  float inv[2];
#pragma unroll
  for (int qt = 0; qt < 2; ++qt) {
    rs2[qt] += __shfl_xor(rs2[qt], 16, 64);
    rs2[qt] += __shfl_xor(rs2[qt], 32, 64);
    inv[qt] = 1.f / rs2[qt];
  }

  // epilogue: O^T -> [q][d] via wave-private LDS (reuse smem), coalesced stores
  __syncthreads();                       // all waves done reading Ks/Vts/P
  u16* Ob = smem + wv * 2304;            // 32 rows x pitch 72 per wave (8*2304 <= 28160)
#pragma unroll
  for (int qt = 0; qt < 2; ++qt)
#pragma unroll
    for (int mt = 0; mt < 4; ++mt) {
      u16 e[4];
#pragma unroll
      for (int r = 0; r < 4; ++r) e[r] = f2b(Oa[mt][qt][r] * inv[qt]);
      uint2v pw;
      pw[0] = (unsigned)e[0] | ((unsigned)e[1] << 16);
      pw[1] = (unsigned)e[2] | ((unsigned)e[3] << 16);
      *(uint2v*)(Ob + (qt * 16 + ln) * 72 + mt * 16 + q8 * 4) = pw;
    }
  // no barrier: wave-private round-trip
#pragma unroll
  for (int p = 0; p < 4; ++p) {
    int row = p * 8 + (lane >> 3);
    int c8 = (lane & 7) * 8;
    short8 v = *(const short8*)(Ob + row * 72 + c8);
    int q = q0 + wv * 32 + row;
    *(short8*)(ctxb + ((size_t)(b * S_ + q)) * HID_ + h * 64 + c8) = v;
  }
}

// ---------------- output projection GEMM, D[o][s], BK=64; +bias +residual ----
__global__ __launch_bounds__(256) void gemm_out(
    const u16* __restrict__ W, const u16* __restrict__ X,
    const float* __restrict__ bout, const float* __restrict__ xres,
    u16* __restrict__ hb) {
  constexpr int K = HID_;
  __shared__ u16 smem[128 * 136];
  u16* Ws0 = smem;
  u16* Ws1 = smem + 4096;
  u16* Xs0 = smem + 8192;
  u16* Xs1 = smem + 12288;
  const int lin = blockIdx.x;
  const int virt = (lin & 7) * 64 + (lin >> 3);
  const int o0 = (virt % 8) * 128, s0 = (virt / 8) * 128;
  const int t = threadIdx.x, lane = t & 63, wv = t >> 6;
  const int wr = wv >> 1, wc = wv & 1, ln = lane & 15, q8 = lane >> 4;
  f32x4 acc[4][4] = {};

  for (int kt = 0; kt < K / 64; ++kt) {
    const int k0 = kt * 64;
#pragma unroll
    for (int c = 0; c < 2; ++c) {
      int idx = c * 256 + t, row = idx >> 2, cc = (idx & 3) * 8;
      const int db = (c * 256 + wv * 64) * 8;
      llds16(W + (size_t)(o0 + row) * K + k0 + cc,      Ws0 + db);
      llds16(W + (size_t)(o0 + row) * K + k0 + 32 + cc, Ws1 + db);
      llds16(X + (size_t)(s0 + row) * K + k0 + cc,      Xs0 + db);
      llds16(X + (size_t)(s0 + row) * K + k0 + 32 + cc, Xs1 + db);
    }
    __syncthreads();
#pragma unroll
    for (int hh = 0; hh < 2; ++hh) {
      const u16* Wh = hh ? Ws1 : Ws0;
      const u16* Xh = hh ? Xs1 : Xs0;
      short8 of[4], sf[4];
#pragma unroll
      for (int mi = 0; mi < 4; ++mi)
        of[mi] = *(const short8*)(Wh + (wr * 64 + mi * 16 + ln) * 32 + q8 * 8);
#pragma unroll
      for (int ni = 0; ni < 4; ++ni)
        sf[ni] = *(const short8*)(Xh + (wc * 64 + ni * 16 + ln) * 32 + q8 * 8);
#pragma unroll
      for (int mi = 0; mi < 4; ++mi)
#pragma unroll
        for (int ni = 0; ni < 4; ++ni)
          acc[mi][ni] = __builtin_amdgcn_mfma_f32_16x16x32_bf16(of[mi], sf[ni], acc[mi][ni], 0, 0, 0);
    }
    __syncthreads();
  }

  // phase 1: acc + bias -> bf16 into buf[s][o]
#pragma unroll
  for (int mi = 0; mi < 4; ++mi) {
    const int ocol = wr * 64 + mi * 16 + q8 * 4;
    float4 b4 = *(const float4*)(bout + o0 + ocol);
#pragma unroll
    for (int ni = 0; ni < 4; ++ni) {
      const int srow = wc * 64 + ni * 16 + ln;
      u16 e[4];
#pragma unroll
      for (int r = 0; r < 4; ++r) e[r] = f2b(acc[mi][ni][r] + ((const float*)&b4)[r]);
      uint2v pw;
      pw[0] = (unsigned)e[0] | ((unsigned)e[1] << 16);
      pw[1] = (unsigned)e[2] | ((unsigned)e[3] << 16);
      *(uint2v*)(smem + srow * 136 + ocol) = pw;
    }
  }
  __syncthreads();
  // phase 2: +residual (coalesced fp32 reads), coalesced 16B stores
#pragma unroll
  for (int i = 0; i < 8; ++i) {
    int flat = i * 256 + t;
    int srow = flat >> 4, c8 = (flat & 15) * 8;
    short8 v = *(const short8*)(smem + srow * 136 + c8);
    int s = s0 + srow, o = o0 + c8;
    float4 x0 = *(const float4*)(xres + (size_t)s * HID_ + o);
    float4 x1 = *(const float4*)(xres + (size_t)s * HID_ + o + 4);
    short8 st;
#pragma unroll
    for (int j = 0; j < 4; ++j) st[j] = (short)f2b(b2f((u16)v[j]) + ((const float*)&x0)[j]);
#pragma unroll
    for (int j = 0; j < 4; ++j) st[4 + j] = (short)f2b(b2f((u16)v[4 + j]) + ((const float*)&x1)[j]);
    *(short8*)(hb + (size_t)s * HID_ + o) = st;
  }
}

// ---------------- LayerNorm: one 256-thread block per row, float4 stores ------
__global__ __launch_bounds__(256) void ln_kernel(
    const u16* __restrict__ hb, const float* __restrict__ gamma,
    const float* __restrict__ beta, float* __restrict__ out) {
  __shared__ float red[8];
  const int t = threadIdx.x, lane = t & 63, wv = t >> 6;
  const int row = blockIdx.x;
  const u16* hr = hb + (size_t)row * HID_;
  ushort4v a = *(const ushort4v*)(hr + t * 4);
  float v[4];
#pragma unroll
  for (int j = 0; j < 4; ++j) v[j] = b2f(a[j]);
  float sum = (v[0] + v[1]) + (v[2] + v[3]);
  float sq = (v[0] * v[0] + v[1] * v[1]) + (v[2] * v[2] + v[3] * v[3]);
#pragma unroll
  for (int off = 1; off < 64; off <<= 1) {
    sum += __shfl_xor(sum, off, 64);
    sq  += __shfl_xor(sq, off, 64);
  }
  if (lane == 0) { red[wv] = sum; red[4 + wv] = sq; }
  __syncthreads();
  const float s4 = (red[0] + red[1]) + (red[2] + red[3]);
  const float q4 = (red[4] + red[5]) + (red[6] + red[7]);
  const float mu = s4 * (1.f / HID_);
  const float var = q4 * (1.f / HID_) - mu * mu;
  const float inv = 1.f / sqrtf(var + 1e-12f);
  float4 g = *(const float4*)(gamma + t * 4);
  float4 be = *(const float4*)(beta + t * 4);
  float4 o;
  o.x = (v[0] - mu) * inv * g.x + be.x;
  o.y = (v[1] - mu) * inv * g.y + be.y;
  o.z = (v[2] - mu) * inv * g.z + be.z;
  o.w = (v[3] - mu) * inv * g.w + be.w;
  *(float4*)(out + (size_t)row * HID_ + t * 4) = o;
}

extern "C" void kernel_launch(void* const* d_in, const int* in_sizes, int n_in,
                              void* d_out, int out_size, void* d_ws, size_t ws_size,
                              hipStream_t stream) {
  (void)in_sizes; (void)n_in; (void)out_size; (void)ws_size;
  const float* x     = (const float*)d_in[0];
  const unsigned char* mask = (const unsigned char*)d_in[1];
  const float* relp  = (const float*)d_in[2];
  const float* rel2  = (const float*)d_in[3];
  const float* wqkv  = (const float*)d_in[4];
  const float* qbias = (const float*)d_in[5];
  const float* vbias = (const float*)d_in[6];
  const float* wout  = (const float*)d_in[7];
  const float* bout  = (const float*)d_in[8];
  const float* gamma = (const float*)d_in[9];
  const float* beta  = (const float*)d_in[10];
  float* out = (float*)d_out;

  char* ws = (char*)d_ws;
  const size_t MB = (size_t)1 << 20;
  u16* xb    = (u16*)(ws + 0 * MB);    // 16 MB
  u16* wqkvb = (u16*)(ws + 16 * MB);   // 6 MB
  u16* woutb = (u16*)(ws + 22 * MB);   // 2 MB
  u16* Qb    = (u16*)(ws + 56 * MB);   // 16 MB
  u16* Kb    = (u16*)(ws + 72 * MB);   // 16 MB
  u16* Vtb   = (u16*)(ws + 88 * MB);   // 16 MB  [B,NH,HD,S] (written by gemm_qkv)
  u16* ctxb  = (u16*)(ws + 104 * MB);  // 16 MB
  u16* hb    = (u16*)(ws + 120 * MB);  // 16 MB

  prep_cvt<<<2048, 256, 0, stream>>>(x, wqkv, wout, xb, wqkvb, woutb);
  gemm_qkv<<<1536, 256, 0, stream>>>(wqkvb, xb, qbias, vbias, Qb, Kb, Vtb);
  flash_attn<<<512, 512, 0, stream>>>(Qb, Kb, Vtb, relp, rel2, mask, ctxb);
  gemm_out<<<512, 256, 0, stream>>>(woutb, ctxb, bout, x, hb);
  ln_kernel<<<8192, 256, 0, stream>>>(hb, gamma, beta, out);
}

// Round 9
// 389.027 us; speedup vs baseline: 1.1511x; 1.1511x over previous
//
#include <hip/hip_runtime.h>
#include <stdint.h>
#include <stddef.h>

typedef unsigned short u16;
typedef __attribute__((ext_vector_type(8))) short short8;
typedef __attribute__((ext_vector_type(4))) float f32x4;
typedef __attribute__((ext_vector_type(4))) unsigned short ushort4v;
typedef __attribute__((ext_vector_type(4))) unsigned char uchar4v;
typedef __attribute__((ext_vector_type(2))) unsigned int uint2v;

constexpr int B_ = 8, S_ = 1024, HID_ = 1024, NH_ = 16, HD_ = 64;
// log2(e) folded into Q-scale / rel / shift so softmax is a bare v_exp_f32 (exp2).
#define LOG2E_F 1.4426950408889634f
#define QSCALE_F 0.18033688011112043f   /* 0.125 * log2(e) */
#define SHIFT2_F 11.541560327111707f    /* 8 * log2(e) */

__device__ __forceinline__ u16 f2b(float f) {
  unsigned int u = __builtin_bit_cast(unsigned int, f);
  u += 0x7fff + ((u >> 16) & 1);   // RNE
  return (u16)(u >> 16);
}
__device__ __forceinline__ float b2f(u16 s) {
  unsigned int u = ((unsigned int)s) << 16;
  return __builtin_bit_cast(float, u);
}
// 2^x. MUST be compiler-emitted (trans-op read hazard: inline-asm v_exp_f32 is
// invisible to the hazard recognizer -> stale-register reads; caused r2/r3 fails).
__device__ __forceinline__ float fexp2(float x) {
#if __has_builtin(__builtin_amdgcn_exp2f)
  return __builtin_amdgcn_exp2f(x);
#else
  return exp2f(x);
#endif
}
__device__ __forceinline__ void llds16(const void* g, void* l) {
  __builtin_amdgcn_global_load_lds((__attribute__((address_space(1))) void*)g,
                                   (__attribute__((address_space(3))) void*)l, 16, 0, 0);
}

// ---------------- fp32 -> bf16 conversions (8 floats/thread, 16B stores) -------
__global__ __launch_bounds__(256) void prep_cvt(
    const float* __restrict__ x, const float* __restrict__ wqkv,
    const float* __restrict__ wout, u16* __restrict__ xb,
    u16* __restrict__ wqkvb, u16* __restrict__ woutb) {
  const int NX8 = B_ * S_ * HID_ / 8, NW18 = 3 * HID_ * HID_ / 8, NW28 = HID_ * HID_ / 8;
  const int tot = NX8 + NW18 + NW28;
  for (int i = blockIdx.x * blockDim.x + threadIdx.x; i < tot; i += gridDim.x * blockDim.x) {
    const float4* s; u16* d; int j;
    if (i < NX8)              { s = (const float4*)x;    d = xb;    j = i; }
    else if (i < NX8 + NW18)  { s = (const float4*)wqkv; d = wqkvb; j = i - NX8; }
    else                      { s = (const float4*)wout; d = woutb; j = i - NX8 - NW18; }
    float4 v0 = s[2 * (size_t)j], v1 = s[2 * (size_t)j + 1];
    short8 o;
    o[0] = (short)f2b(v0.x); o[1] = (short)f2b(v0.y);
    o[2] = (short)f2b(v0.z); o[3] = (short)f2b(v0.w);
    o[4] = (short)f2b(v1.x); o[5] = (short)f2b(v1.y);
    o[6] = (short)f2b(v1.z); o[7] = (short)f2b(v1.w);
    *(short8*)(d + 8 * (size_t)j) = o;
  }
}

// ---------------- rel_pos + rel_2d_pos -> bf16 (pre-scaled by log2e), permuted ----
// elem (h,q,k): ktg=k>>4, qtg=q>>4, qk=(k&15)>>2, rk=k&3, lq=q&15
// flat = (((h*64+ktg)*64+qtg)*4+qk)*64 + lq*4 + rk
__global__ __launch_bounds__(256) void rel_perm(
    const float* __restrict__ a, const float* __restrict__ b, u16* __restrict__ relb) {
  __shared__ u16 lbuf[16 * 1032];
  const int qtg = blockIdx.x, h = blockIdx.y;
  const int t = threadIdx.x;
#pragma unroll
  for (int it = 0; it < 16; ++it) {
    int idx = it * 256 + t;
    int lq = idx >> 8, kc = idx & 255;
    size_t src = ((size_t)h * S_ + qtg * 16 + lq) * S_ + kc * 4;
    float4 va = *(const float4*)(a + src);
    float4 vb = *(const float4*)(b + src);
    ushort4v o;
    o[0] = f2b((va.x + vb.x) * LOG2E_F); o[1] = f2b((va.y + vb.y) * LOG2E_F);
    o[2] = f2b((va.z + vb.z) * LOG2E_F); o[3] = f2b((va.w + vb.w) * LOG2E_F);
    *(ushort4v*)(lbuf + lq * 1032 + kc * 4) = o;
  }
  __syncthreads();
#pragma unroll
  for (int it = 0; it < 16; ++it) {
    int c = it * 16 + (t >> 4);
    int ktg = c >> 2, qk = c & 3, lq = t & 15;
    ushort4v v = *(const ushort4v*)(lbuf + lq * 1032 + ktg * 16 + qk * 4);
    *(ushort4v*)(relb + ((((size_t)h * 64 + ktg) * 64 + qtg) * 4 + qk) * 64 + lq * 4) = v;
  }
}

// ---------------- QKV projection GEMM, D[o][s], BK=64 ----------------
// XCD-chunked 1D grid (1536 = 8*192, o-fastest in chunk).
// Q/K: LDS-transposed coalesced epilogue to [B,NH,S,HD].
// V: transposed epilogue -> Vt[B,NH,HD,S] directly.
__global__ __launch_bounds__(256) void gemm_qkv(
    const u16* __restrict__ W, const u16* __restrict__ X,
    const float* __restrict__ qbias, const float* __restrict__ vbias,
    u16* __restrict__ Qb, u16* __restrict__ Kb, u16* __restrict__ Vtb) {
  constexpr int K = HID_;
  __shared__ u16 smem[128 * 136];           // 4x4096 staging overlaid with epilogue buf
  u16* Ws0 = smem;
  u16* Ws1 = smem + 4096;
  u16* Xs0 = smem + 8192;
  u16* Xs1 = smem + 12288;
  const int lin = blockIdx.x;
  const int virt = (lin & 7) * 192 + (lin >> 3);
  const int o0 = (virt % 24) * 128, s0 = (virt / 24) * 128;
  const int t = threadIdx.x, lane = t & 63, wv = t >> 6;
  const int wr = wv >> 1, wc = wv & 1, ln = lane & 15, q8 = lane >> 4;
  f32x4 acc[4][4] = {};

  for (int kt = 0; kt < K / 64; ++kt) {
    const int k0 = kt * 64;
#pragma unroll
    for (int c = 0; c < 2; ++c) {
      int idx = c * 256 + t, row = idx >> 2, cc = (idx & 3) * 8;
      const int db = (c * 256 + wv * 64) * 8;
      llds16(W + (size_t)(o0 + row) * K + k0 + cc,      Ws0 + db);
      llds16(W + (size_t)(o0 + row) * K + k0 + 32 + cc, Ws1 + db);
      llds16(X + (size_t)(s0 + row) * K + k0 + cc,      Xs0 + db);
      llds16(X + (size_t)(s0 + row) * K + k0 + 32 + cc, Xs1 + db);
    }
    __syncthreads();
#pragma unroll
    for (int hh = 0; hh < 2; ++hh) {
      const u16* Wh = hh ? Ws1 : Ws0;
      const u16* Xh = hh ? Xs1 : Xs0;
      short8 of[4], sf[4];
#pragma unroll
      for (int mi = 0; mi < 4; ++mi)
        of[mi] = *(const short8*)(Wh + (wr * 64 + mi * 16 + ln) * 32 + q8 * 8);
#pragma unroll
      for (int ni = 0; ni < 4; ++ni)
        sf[ni] = *(const short8*)(Xh + (wc * 64 + ni * 16 + ln) * 32 + q8 * 8);
#pragma unroll
      for (int mi = 0; mi < 4; ++mi)
#pragma unroll
        for (int ni = 0; ni < 4; ++ni)
          acc[mi][ni] = __builtin_amdgcn_mfma_f32_16x16x32_bf16(of[mi], sf[ni], acc[mi][ni], 0, 0, 0);
    }
    __syncthreads();
  }

  const int sec = o0 >> 10;   // 0=Q 1=K 2=V (block-uniform)

  if (sec == 2) {
    // ----- V: transposed epilogue, write Vt[b,h,d,s] directly -----
#pragma unroll
    for (int mi = 0; mi < 4; ++mi) {
      const int ocol = wr * 64 + mi * 16 + q8 * 4;
      const int oo = (o0 + ocol) & 1023;
      float4 b4 = *(const float4*)(vbias + oo);
#pragma unroll
      for (int ni = 0; ni < 4; ++ni) {
        const int srow = wc * 64 + ni * 16 + ln;
#pragma unroll
        for (int r = 0; r < 4; ++r)
          smem[(ocol + r) * 136 + srow] = f2b(acc[mi][ni][r] + ((const float*)&b4)[r]);
      }
    }
    __syncthreads();
#pragma unroll
    for (int i = 0; i < 8; ++i) {
      int flat = i * 256 + t;
      int dl = flat >> 4, s8 = (flat & 15) * 8;
      short8 v = *(const short8*)(smem + dl * 136 + s8);
      int oo = (o0 + dl) & 1023, hh = oo >> 6, dd = oo & 63;
      int bb = s0 >> 10, ss = (s0 + s8) & 1023;
      *(short8*)(Vtb + ((size_t)(bb * NH_ + hh) * HD_ + dd) * S_ + ss) = v;
    }
    return;
  }

  // ----- Q/K: phase 1: bias/scale applied, bf16 into buf[s 128][o 128, pitch 136]
#pragma unroll
  for (int mi = 0; mi < 4; ++mi) {
    const int ocol = wr * 64 + mi * 16 + q8 * 4;
    const int oo = (o0 + ocol) & 1023;
    float4 b4;
    if (sec == 0) b4 = *(const float4*)(qbias + oo);
    else          b4 = float4{0.f, 0.f, 0.f, 0.f};
#pragma unroll
    for (int ni = 0; ni < 4; ++ni) {
      const int srow = wc * 64 + ni * 16 + ln;
      u16 e[4];
#pragma unroll
      for (int r = 0; r < 4; ++r) {
        float v = acc[mi][ni][r] + ((const float*)&b4)[r];
        if (sec == 0) v *= QSCALE_F;   // 1/sqrt(64) * log2(e)
        e[r] = f2b(v);
      }
      uint2v pw;
      pw[0] = (unsigned)e[0] | ((unsigned)e[1] << 16);
      pw[1] = (unsigned)e[2] | ((unsigned)e[3] << 16);
      *(uint2v*)(smem + srow * 136 + ocol) = pw;
    }
  }
  __syncthreads();
  u16* dst = (sec == 0) ? Qb : Kb;
#pragma unroll
  for (int i = 0; i < 8; ++i) {
    int flat = i * 256 + t;
    int srow = flat >> 4, c8 = (flat & 15) * 8;
    short8 v = *(const short8*)(smem + srow * 136 + c8);
    int oo = (o0 + c8) & 1023, hh = oo >> 6, dd = oo & 63;
    int s = s0 + srow, bb = s >> 10, ss = s & 1023;
    *(short8*)(dst + ((size_t)(bb * NH_ + hh) * S_ + ss) * HD_ + dd) = v;
  }
}

// ---------------- flash attention: S^T = K·Q^T, fixed-shift softmax, O^T = V^T·P^T ----
// 512 threads (8 waves), 256 q-rows per block, grid 512, XCD-chunked decode.
// Round-7-proven structure: permuted bf16 rel (relb) burst-prefetched per kvc
// chunk — the software pipeline is load-bearing (r8's direct fp32 reads were
// latency-serialized: 80 -> 192 us). launch_bounds(512,2) keeps it spill-free.
__global__ __launch_bounds__(512, 2) void flash_attn(
    const u16* __restrict__ Qb, const u16* __restrict__ Kb,
    const u16* __restrict__ Vtb, const u16* __restrict__ relb,
    const unsigned char* __restrict__ mask, u16* __restrict__ ctxb) {
  const int lin = blockIdx.x;
  const int virt = (lin & 7) * 64 + (lin >> 3);
  const int h = virt >> 5, qt_blk = (virt >> 3) & 3, b = virt & 7;
  const int bh = b * NH_ + h, q0 = qt_blk * 256;
  const int t = threadIdx.x, lane = t & 63, wv = t >> 6;
  const int ln = lane & 15, q8 = lane >> 4;

  __shared__ u16 smem[28160];          // Ks 128*72 | Vts 64*136 | Pbuf 8*32*40 = 55 KB
  u16* Ks  = smem;                     // [k 128][64+8]
  u16* Vts = smem + 9216;              // [d 64][128+8]
  u16* Pw  = smem + 17920 + wv * 1280; // per-wave [q 32][32+8]

  const int krow = t >> 3, kcol = (t & 7) * 8;   // 64 k-rows per pass
  const int vrow = t >> 4, vcol = (t & 15) * 8;  // 32 d-rows per pass

  // per-lane rel base: chunk (kvc) stride is 2 kt-groups = 2*64*4 u16
  const u16* relbase = relb + (((size_t)h * 64) * 64 + (size_t)(qt_blk * 16 + wv * 2)) * 4 * 64
                            + (size_t)q8 * 64 + ln * 4;

  short8 kreg[2], vreg[2];
#pragma unroll
  for (int i = 0; i < 2; ++i)
    kreg[i] = *(const short8*)(Kb + ((size_t)bh * S_ + i * 64 + krow) * HD_ + kcol);
#pragma unroll
  for (int i = 0; i < 2; ++i)
    vreg[i] = *(const short8*)(Vtb + ((size_t)bh * HD_ + i * 32 + vrow) * S_ + vcol);

  short8 qf[2][2];
#pragma unroll
  for (int qt = 0; qt < 2; ++qt)
#pragma unroll
    for (int kc = 0; kc < 2; ++kc)
      qf[qt][kc] = *(const short8*)(Qb + ((size_t)bh * S_ + q0 + wv * 32 + qt * 16 + ln) * HD_ + kc * 32 + q8 * 8);

  f32x4 Oa[4][2] = {};   // [mt(d)][qt]
  float rs2[2] = {0.f, 0.f};

  for (int kt128 = 0; kt128 < 8; ++kt128) {
    const int k0 = kt128 * 128;

    // mask burst (8 VGPRs) + rel chunk 0 prefetch (8 VGPRs); remaining rel
    // chunks are software-pipelined inside the kvc loop (live <=16 VGPRs).
    uchar4v mg[4][2];
#pragma unroll
    for (int kvc = 0; kvc < 4; ++kvc)
#pragma unroll
      for (int sub = 0; sub < 2; ++sub)
        mg[kvc][sub] = *(const uchar4v*)(mask + b * S_ + k0 + (kvc * 2 + sub) * 16 + q8 * 4);

    ushort4v relg[4][2][2];   // [kvc][sub][qt]; fully-unrolled kvc -> static indexing
#pragma unroll
    for (int sub = 0; sub < 2; ++sub)
#pragma unroll
      for (int qt = 0; qt < 2; ++qt)
        relg[0][sub][qt] = *(const ushort4v*)(relbase +
            (((size_t)(kt128 * 8 + sub) * 64 + qt) * 4) * 64);

    __syncthreads();
#pragma unroll
    for (int i = 0; i < 2; ++i)
      *(short8*)(Ks + (i * 64 + krow) * 72 + kcol) = kreg[i];
#pragma unroll
    for (int i = 0; i < 2; ++i)
      *(short8*)(Vts + (i * 32 + vrow) * 136 + vcol) = vreg[i];
    if (kt128 < 7) {
      const int k0n = k0 + 128;
#pragma unroll
      for (int i = 0; i < 2; ++i)
        kreg[i] = *(const short8*)(Kb + ((size_t)bh * S_ + k0n + i * 64 + krow) * HD_ + kcol);
#pragma unroll
      for (int i = 0; i < 2; ++i)
        vreg[i] = *(const short8*)(Vtb + ((size_t)bh * HD_ + i * 32 + vrow) * S_ + k0n + vcol);
    }
    __syncthreads();

#pragma unroll
    for (int kvc = 0; kvc < 4; ++kvc) {
      // prefetch next rel chunk while computing this one
      if (kvc < 3) {
#pragma unroll
        for (int sub = 0; sub < 2; ++sub)
#pragma unroll
          for (int qt = 0; qt < 2; ++qt)
            relg[kvc + 1][sub][qt] = *(const ushort4v*)(relbase +
                (((size_t)(kt128 * 8 + (kvc + 1) * 2 + sub) * 64 + qt) * 4) * 64);
      }
#pragma unroll
      for (int sub = 0; sub < 2; ++sub) {
        const int kt = kvc * 2 + sub;
        short8 kf0 = *(const short8*)(Ks + (kt * 16 + ln) * 72 + q8 * 8);
        short8 kf1 = *(const short8*)(Ks + (kt * 16 + ln) * 72 + 32 + q8 * 8);
        uchar4v m4 = mg[kvc][sub];
        f32x4 mbase;
#pragma unroll
        for (int r = 0; r < 4; ++r) mbase[r] = (m4[r] ? -1e30f : 0.f) - SHIFT2_F;
#pragma unroll
        for (int qt = 0; qt < 2; ++qt) {
          ushort4v r4 = relg[kvc][sub][qt];
          f32x4 sc;
#pragma unroll
          for (int r = 0; r < 4; ++r) sc[r] = b2f(r4[r]) + mbase[r];
          sc = __builtin_amdgcn_mfma_f32_16x16x32_bf16(kf0, qf[qt][0], sc, 0, 0, 0);
          sc = __builtin_amdgcn_mfma_f32_16x16x32_bf16(kf1, qf[qt][1], sc, 0, 0, 0);
          // scores pre-scaled by log2(e): single hardware v_exp_f32 each
          float p0 = fexp2(sc[0]), p1 = fexp2(sc[1]);
          float p2 = fexp2(sc[2]), p3 = fexp2(sc[3]);
          rs2[qt] += (p0 + p1) + (p2 + p3);
          uint2v pw;
          pw[0] = (unsigned)f2b(p0) | ((unsigned)f2b(p1) << 16);
          pw[1] = (unsigned)f2b(p2) | ((unsigned)f2b(p3) << 16);
          *(uint2v*)(Pw + (qt * 16 + ln) * 40 + sub * 16 + q8 * 4) = pw;
        }
      }
      short8 pf0 = *(const short8*)(Pw + ln * 40 + q8 * 8);
      short8 pf1 = *(const short8*)(Pw + (16 + ln) * 40 + q8 * 8);
#pragma unroll
      for (int mt = 0; mt < 4; ++mt) {
        short8 vf = *(const short8*)(Vts + (mt * 16 + ln) * 136 + kvc * 32 + q8 * 8);
        Oa[mt][0] = __builtin_amdgcn_mfma_f32_16x16x32_bf16(vf, pf0, Oa[mt][0], 0, 0, 0);
        Oa[mt][1] = __builtin_amdgcn_mfma_f32_16x16x32_bf16(vf, pf1, Oa[mt][1], 0, 0, 0);
      }
    }
  }

  float inv[2];
#pragma unroll
  for (int qt = 0; qt < 2; ++qt) {
    rs2[qt] += __shfl_xor(rs2[qt], 16, 64);
    rs2[qt] += __shfl_xor(rs2[qt], 32, 64);
    inv[qt] = 1.f / rs2[qt];
  }

  // epilogue: O^T -> [q][d] via wave-private LDS (reuse smem), coalesced stores
  __syncthreads();                       // all waves done reading Ks/Vts/P
  u16* Ob = smem + wv * 2304;            // 32 rows x pitch 72 per wave (8*2304 <= 28160)
#pragma unroll
  for (int qt = 0; qt < 2; ++qt)
#pragma unroll
    for (int mt = 0; mt < 4; ++mt) {
      u16 e[4];
#pragma unroll
      for (int r = 0; r < 4; ++r) e[r] = f2b(Oa[mt][qt][r] * inv[qt]);
      uint2v pw;
      pw[0] = (unsigned)e[0] | ((unsigned)e[1] << 16);
      pw[1] = (unsigned)e[2] | ((unsigned)e[3] << 16);
      *(uint2v*)(Ob + (qt * 16 + ln) * 72 + mt * 16 + q8 * 4) = pw;
    }
  // no barrier: wave-private round-trip
#pragma unroll
  for (int p = 0; p < 4; ++p) {
    int row = p * 8 + (lane >> 3);
    int c8 = (lane & 7) * 8;
    short8 v = *(const short8*)(Ob + row * 72 + c8);
    int q = q0 + wv * 32 + row;
    *(short8*)(ctxb + ((size_t)(b * S_ + q)) * HID_ + h * 64 + c8) = v;
  }
}

// ---------------- output projection GEMM, D[o][s], BK=64; +bias +residual ----
__global__ __launch_bounds__(256) void gemm_out(
    const u16* __restrict__ W, const u16* __restrict__ X,
    const float* __restrict__ bout, const float* __restrict__ xres,
    u16* __restrict__ hb) {
  constexpr int K = HID_;
  __shared__ u16 smem[128 * 136];
  u16* Ws0 = smem;
  u16* Ws1 = smem + 4096;
  u16* Xs0 = smem + 8192;
  u16* Xs1 = smem + 12288;
  const int lin = blockIdx.x;
  const int virt = (lin & 7) * 64 + (lin >> 3);
  const int o0 = (virt % 8) * 128, s0 = (virt / 8) * 128;
  const int t = threadIdx.x, lane = t & 63, wv = t >> 6;
  const int wr = wv >> 1, wc = wv & 1, ln = lane & 15, q8 = lane >> 4;
  f32x4 acc[4][4] = {};

  for (int kt = 0; kt < K / 64; ++kt) {
    const int k0 = kt * 64;
#pragma unroll
    for (int c = 0; c < 2; ++c) {
      int idx = c * 256 + t, row = idx >> 2, cc = (idx & 3) * 8;
      const int db = (c * 256 + wv * 64) * 8;
      llds16(W + (size_t)(o0 + row) * K + k0 + cc,      Ws0 + db);
      llds16(W + (size_t)(o0 + row) * K + k0 + 32 + cc, Ws1 + db);
      llds16(X + (size_t)(s0 + row) * K + k0 + cc,      Xs0 + db);
      llds16(X + (size_t)(s0 + row) * K + k0 + 32 + cc, Xs1 + db);
    }
    __syncthreads();
#pragma unroll
    for (int hh = 0; hh < 2; ++hh) {
      const u16* Wh = hh ? Ws1 : Ws0;
      const u16* Xh = hh ? Xs1 : Xs0;
      short8 of[4], sf[4];
#pragma unroll
      for (int mi = 0; mi < 4; ++mi)
        of[mi] = *(const short8*)(Wh + (wr * 64 + mi * 16 + ln) * 32 + q8 * 8);
#pragma unroll
      for (int ni = 0; ni < 4; ++ni)
        sf[ni] = *(const short8*)(Xh + (wc * 64 + ni * 16 + ln) * 32 + q8 * 8);
#pragma unroll
      for (int mi = 0; mi < 4; ++mi)
#pragma unroll
        for (int ni = 0; ni < 4; ++ni)
          acc[mi][ni] = __builtin_amdgcn_mfma_f32_16x16x32_bf16(of[mi], sf[ni], acc[mi][ni], 0, 0, 0);
    }
    __syncthreads();
  }

  // phase 1: acc + bias -> bf16 into buf[s][o]
#pragma unroll
  for (int mi = 0; mi < 4; ++mi) {
    const int ocol = wr * 64 + mi * 16 + q8 * 4;
    float4 b4 = *(const float4*)(bout + o0 + ocol);
#pragma unroll
    for (int ni = 0; ni < 4; ++ni) {
      const int srow = wc * 64 + ni * 16 + ln;
      u16 e[4];
#pragma unroll
      for (int r = 0; r < 4; ++r) e[r] = f2b(acc[mi][ni][r] + ((const float*)&b4)[r]);
      uint2v pw;
      pw[0] = (unsigned)e[0] | ((unsigned)e[1] << 16);
      pw[1] = (unsigned)e[2] | ((unsigned)e[3] << 16);
      *(uint2v*)(smem + srow * 136 + ocol) = pw;
    }
  }
  __syncthreads();
  // phase 2: +residual (coalesced fp32 reads), coalesced 16B stores
#pragma unroll
  for (int i = 0; i < 8; ++i) {
    int flat = i * 256 + t;
    int srow = flat >> 4, c8 = (flat & 15) * 8;
    short8 v = *(const short8*)(smem + srow * 136 + c8);
    int s = s0 + srow, o = o0 + c8;
    float4 x0 = *(const float4*)(xres + (size_t)s * HID_ + o);
    float4 x1 = *(const float4*)(xres + (size_t)s * HID_ + o + 4);
    short8 st;
#pragma unroll
    for (int j = 0; j < 4; ++j) st[j] = (short)f2b(b2f((u16)v[j]) + ((const float*)&x0)[j]);
#pragma unroll
    for (int j = 0; j < 4; ++j) st[4 + j] = (short)f2b(b2f((u16)v[4 + j]) + ((const float*)&x1)[j]);
    *(short8*)(hb + (size_t)s * HID_ + o) = st;
  }
}

// ---------------- LayerNorm: one 256-thread block per row, float4 stores ------
__global__ __launch_bounds__(256) void ln_kernel(
    const u16* __restrict__ hb, const float* __restrict__ gamma,
    const float* __restrict__ beta, float* __restrict__ out) {
  __shared__ float red[8];
  const int t = threadIdx.x, lane = t & 63, wv = t >> 6;
  const int row = blockIdx.x;
  const u16* hr = hb + (size_t)row * HID_;
  ushort4v a = *(const ushort4v*)(hr + t * 4);
  float v[4];
#pragma unroll
  for (int j = 0; j < 4; ++j) v[j] = b2f(a[j]);
  float sum = (v[0] + v[1]) + (v[2] + v[3]);
  float sq = (v[0] * v[0] + v[1] * v[1]) + (v[2] * v[2] + v[3] * v[3]);
#pragma unroll
  for (int off = 1; off < 64; off <<= 1) {
    sum += __shfl_xor(sum, off, 64);
    sq  += __shfl_xor(sq, off, 64);
  }
  if (lane == 0) { red[wv] = sum; red[4 + wv] = sq; }
  __syncthreads();
  const float s4 = (red[0] + red[1]) + (red[2] + red[3]);
  const float q4 = (red[4] + red[5]) + (red[6] + red[7]);
  const float mu = s4 * (1.f / HID_);
  const float var = q4 * (1.f / HID_) - mu * mu;
  const float inv = 1.f / sqrtf(var + 1e-12f);
  float4 g = *(const float4*)(gamma + t * 4);
  float4 be = *(const float4*)(beta + t * 4);
  float4 o;
  o.x = (v[0] - mu) * inv * g.x + be.x;
  o.y = (v[1] - mu) * inv * g.y + be.y;
  o.z = (v[2] - mu) * inv * g.z + be.z;
  o.w = (v[3] - mu) * inv * g.w + be.w;
  *(float4*)(out + (size_t)row * HID_ + t * 4) = o;
}

extern "C" void kernel_launch(void* const* d_in, const int* in_sizes, int n_in,
                              void* d_out, int out_size, void* d_ws, size_t ws_size,
                              hipStream_t stream) {
  (void)in_sizes; (void)n_in; (void)out_size; (void)ws_size;
  const float* x     = (const float*)d_in[0];
  const unsigned char* mask = (const unsigned char*)d_in[1];
  const float* relp  = (const float*)d_in[2];
  const float* rel2  = (const float*)d_in[3];
  const float* wqkv  = (const float*)d_in[4];
  const float* qbias = (const float*)d_in[5];
  const float* vbias = (const float*)d_in[6];
  const float* wout  = (const float*)d_in[7];
  const float* bout  = (const float*)d_in[8];
  const float* gamma = (const float*)d_in[9];
  const float* beta  = (const float*)d_in[10];
  float* out = (float*)d_out;

  char* ws = (char*)d_ws;
  const size_t MB = (size_t)1 << 20;
  u16* xb    = (u16*)(ws + 0 * MB);    // 16 MB
  u16* wqkvb = (u16*)(ws + 16 * MB);   // 6 MB
  u16* woutb = (u16*)(ws + 22 * MB);   // 2 MB
  u16* relb  = (u16*)(ws + 24 * MB);   // 32 MB (permuted, pre-scaled by log2e)
  u16* Qb    = (u16*)(ws + 56 * MB);   // 16 MB
  u16* Kb    = (u16*)(ws + 72 * MB);   // 16 MB
  u16* Vtb   = (u16*)(ws + 88 * MB);   // 16 MB  [B,NH,HD,S] (written by gemm_qkv)
  u16* ctxb  = (u16*)(ws + 104 * MB);  // 16 MB
  u16* hb    = (u16*)(ws + 120 * MB);  // 16 MB

  prep_cvt<<<2048, 256, 0, stream>>>(x, wqkv, wout, xb, wqkvb, woutb);
  rel_perm<<<dim3(64, 16), 256, 0, stream>>>(relp, rel2, relb);
  gemm_qkv<<<1536, 256, 0, stream>>>(wqkvb, xb, qbias, vbias, Qb, Kb, Vtb);
  flash_attn<<<512, 512, 0, stream>>>(Qb, Kb, Vtb, relb, mask, ctxb);
  gemm_out<<<512, 256, 0, stream>>>(woutb, ctxb, bout, x, hb);
  ln_kernel<<<8192, 256, 0, stream>>>(hb, gamma, beta, out);
}